// Round 7
// baseline (824.563 us; speedup 1.0000x reference)
//
#include <hip/hip_runtime.h>
#include <hip/hip_bf16.h>

// EdgeAwareCritic: 3x GATv2 (H=2 heads, HID=128) + FiLM + MLP head, scalar output.
// fp32 inputs; GEMMs in bf16 MFMA. GAT: single fused node-centric kernel
// (logit pass -> LDS stash, exact softmax, aggregate pass re-reads L2-hot rows).

typedef __attribute__((ext_vector_type(8))) short bf16x8;   // 8 bf16 = 4 VGPR
typedef __attribute__((ext_vector_type(4))) float f32x4;

__device__ __forceinline__ unsigned short f2bf(float f) {
    union { float f; unsigned int i; } v; v.f = f;
    unsigned int x = v.i;
    x += 0x7fffu + ((x >> 16) & 1u);   // round-to-nearest-even
    return (unsigned short)(x >> 16);
}
__device__ __forceinline__ float4 b4f(ushort4 u) {
    union { unsigned int i; float f; } a, b, c, d;
    a.i = (unsigned int)u.x << 16; b.i = (unsigned int)u.y << 16;
    c.i = (unsigned int)u.z << 16; d.i = (unsigned int)u.w << 16;
    return make_float4(a.f, b.f, c.f, d.f);
}

// ---------------- multi-tensor fp32 -> bf16 convert (RNE) ----------------
#define MAXCVT 12
struct CvtDescs {
    const float* src[MAXCVT];
    unsigned short* dst[MAXCVT];
    int n4[MAXCVT];
    int cnt;
};
__global__ __launch_bounds__(256) void cvt_many_kernel(CvtDescs d) {
    const int tid = blockIdx.x * blockDim.x + threadIdx.x;
    const int stride = gridDim.x * blockDim.x;
    for (int e = 0; e < d.cnt; ++e) {
        const float4* s = (const float4*)d.src[e];
        ushort4* o = (ushort4*)d.dst[e];
        const int n = d.n4[e];
        for (int i = tid; i < n; i += stride) {
            float4 v = s[i];
            o[i] = make_ushort4(f2bf(v.x), f2bf(v.y), f2bf(v.z), f2bf(v.w));
        }
    }
}

// ---------------- CSR build ----------------
__global__ void hist_kernel(const int* __restrict__ dst, int* __restrict__ deg, int n) {
    int i = blockIdx.x * blockDim.x + threadIdx.x;
    if (i < n) atomicAdd(&deg[dst[i]], 1);
}

__global__ __launch_bounds__(1024) void scan_kernel(const int* __restrict__ deg,
                                                    int* __restrict__ rowp,
                                                    int* __restrict__ cur, int n) {
    __shared__ int sums[1024];
    const int t = threadIdx.x;
    const int PER = 20;
    int base = t * PER;
    int local[PER];
    int run = 0;
#pragma unroll
    for (int i = 0; i < PER; ++i) {
        int v = (base + i < n) ? deg[base + i] : 0;
        local[i] = run; run += v;
    }
    sums[t] = run; __syncthreads();
    for (int off = 1; off < 1024; off <<= 1) {
        int v = (t >= off) ? sums[t - off] : 0;
        __syncthreads();
        sums[t] += v;
        __syncthreads();
    }
    int offs = (t > 0) ? sums[t - 1] : 0;
#pragma unroll
    for (int i = 0; i < PER; ++i) {
        int idx = base + i;
        if (idx < n) { int v = offs + local[i]; rowp[idx] = v; cur[idx] = v; }
    }
    if (t == 0) rowp[n] = sums[1023];
}

// scatter: CSR src list + gather edge_attr rows into CSR order (reused by all layers)
__global__ void scatter_kernel(const int* __restrict__ src, const int* __restrict__ dst,
                               int* __restrict__ cur, const float4* __restrict__ ea,
                               int* __restrict__ csrs, float4* __restrict__ eacsr, int n) {
    int i = blockIdx.x * blockDim.x + threadIdx.x;
    if (i < n) {
        int d = dst[i];
        int p = atomicAdd(&cur[d], 1);
        csrs[p] = src[i];
        const float4* er = ea + (size_t)i * 4;
        float4* eo = eacsr + (size_t)p * 4;
        eo[0] = er[0]; eo[1] = er[1]; eo[2] = er[2]; eo[3] = er[3];
    }
}

// ---------------- bf16 MFMA GEMM: C[M,N] = A[M,K]bf16 @ W[N,K]bf16^T + bias ----
template <bool RELU, bool WF32, bool WBF16>
__global__ __launch_bounds__(256) void gemm_mfma_kernel(
    const unsigned short* __restrict__ A, const unsigned short* __restrict__ W,
    const float* __restrict__ bias0, const float* __restrict__ bias1, int bsplit,
    float* __restrict__ C, unsigned short* __restrict__ Cbf, int M, int N, int K) {
    const int t = threadIdx.x;
    const int wave = t >> 6, lane = t & 63;
    const int lo = lane & 15, quad = lane >> 4;
    const int m0 = blockIdx.y * 128 + wave * 32;
    const int n0 = blockIdx.x * 64;

    f32x4 acc[2][4];
#pragma unroll
    for (int i = 0; i < 2; ++i)
#pragma unroll
        for (int j = 0; j < 4; ++j) acc[i][j] = (f32x4){0.f, 0.f, 0.f, 0.f};

    for (int k0 = 0; k0 < K; k0 += 32) {
        bf16x8 af[2], bfr[4];
#pragma unroll
        for (int mi = 0; mi < 2; ++mi) {
            const int mb = m0 + mi * 16;
            if (mb < M)
                af[mi] = *(const bf16x8*)(A + (size_t)(mb + lo) * K + k0 + quad * 8);
            else
                af[mi] = (bf16x8){0, 0, 0, 0, 0, 0, 0, 0};
        }
#pragma unroll
        for (int ni = 0; ni < 4; ++ni)
            bfr[ni] = *(const bf16x8*)(W + (size_t)(n0 + ni * 16 + lo) * K + k0 + quad * 8);
#pragma unroll
        for (int mi = 0; mi < 2; ++mi)
#pragma unroll
            for (int ni = 0; ni < 4; ++ni)
                acc[mi][ni] = __builtin_amdgcn_mfma_f32_16x16x32_bf16(af[mi], bfr[ni], acc[mi][ni], 0, 0, 0);
    }

    float bn[4];
#pragma unroll
    for (int ni = 0; ni < 4; ++ni) {
        const int n = n0 + ni * 16 + lo;
        const float* bp = (n < bsplit) ? bias0 : bias1;
        const int bi = (n < bsplit) ? n : n - bsplit;
        bn[ni] = bp[bi];
    }
#pragma unroll
    for (int mi = 0; mi < 2; ++mi) {
        const int mb = m0 + mi * 16;
        if (mb >= M) continue;
#pragma unroll
        for (int ni = 0; ni < 4; ++ni) {
            const int n = n0 + ni * 16 + lo;
#pragma unroll
            for (int r = 0; r < 4; ++r) {
                float o = acc[mi][ni][r] + bn[ni];
                if (RELU) o = fmaxf(o, 0.f);
                const size_t idx = (size_t)(mb + quad * 4 + r) * N + n;
                if (WF32) C[idx] = o;
                if (WBF16) Cbf[idx] = f2bf(o);
            }
        }
    }
}

// ---------------- fp32 vector GEMM (only for ap: K=16) ----------------
template <int BK, bool RELU, bool WBF16>
__global__ __launch_bounds__(256) void gemm_kernel(const float* __restrict__ A,
                                                   const float* __restrict__ W,
                                                   const float* __restrict__ bp,
                                                   float* __restrict__ C,
                                                   unsigned short* __restrict__ Cbf,
                                                   int M, int N, int K) {
    __shared__ float As[BK][68];
    __shared__ float Ws[BK][68];
    const int t = threadIdx.x;
    const int m0 = blockIdx.y * 64;
    const int n0 = blockIdx.x * 64;
    const int tx = t & 15, ty = t >> 4;
    float acc[4][4];
#pragma unroll
    for (int i = 0; i < 4; ++i)
#pragma unroll
        for (int j = 0; j < 4; ++j) acc[i][j] = 0.f;

    for (int k0 = 0; k0 < K; k0 += BK) {
        const int r = t >> 2, cc = (t & 3) * 4;
        const int arow = m0 + r;
        float4 av = (arow < M) ? *(const float4*)(A + (size_t)arow * K + k0 + cc)
                               : make_float4(0.f, 0.f, 0.f, 0.f);
        As[cc + 0][r] = av.x; As[cc + 1][r] = av.y;
        As[cc + 2][r] = av.z; As[cc + 3][r] = av.w;
        float4 wv = *(const float4*)(W + (size_t)(n0 + r) * K + k0 + cc);
        Ws[cc + 0][r] = wv.x; Ws[cc + 1][r] = wv.y;
        Ws[cc + 2][r] = wv.z; Ws[cc + 3][r] = wv.w;
        __syncthreads();
#pragma unroll
        for (int k = 0; k < BK; ++k) {
            float4 a4 = *(const float4*)&As[k][ty * 4];
            float4 b4 = *(const float4*)&Ws[k][tx * 4];
            float a_[4] = {a4.x, a4.y, a4.z, a4.w};
            float b_[4] = {b4.x, b4.y, b4.z, b4.w};
#pragma unroll
            for (int i = 0; i < 4; ++i)
#pragma unroll
                for (int j = 0; j < 4; ++j) acc[i][j] += a_[i] * b_[j];
        }
        __syncthreads();
    }
    float4 bj = *(const float4*)(bp + n0 + tx * 4);
    float bb[4] = {bj.x, bj.y, bj.z, bj.w};
#pragma unroll
    for (int i = 0; i < 4; ++i) {
        int row = m0 + ty * 4 + i;
        if (row < M) {
            float o[4];
#pragma unroll
            for (int j = 0; j < 4; ++j) {
                o[j] = acc[i][j] + bb[j];
                if (RELU) o[j] = fmaxf(o[j], 0.f);
            }
            *(float4*)(C + (size_t)row * N + n0 + tx * 4) = make_float4(o[0], o[1], o[2], o[3]);
            if (WBF16)
                *(ushort4*)(Cbf + (size_t)row * N + n0 + tx * 4) =
                    make_ushort4(f2bf(o[0]), f2bf(o[1]), f2bf(o[2]), f2bf(o[3]));
        }
    }
}

// ---------------- fused GATv2: one wave per dst node ----------------
// Pass 1: per-edge logits (xl gather + register-We em), stash to LDS (cap 512,
// global spill fallback) — no loop-carried dependency.
// Pass 2: exact per-head softmax stats over stash (lanes 0-31 h0, 32-63 h1).
// Pass 3: weighted aggregate re-reading xl rows (L1/L2-hot from pass 1).
#define GCAP 512
__global__ __launch_bounds__(256) void gat_fused_kernel(
    const unsigned short* __restrict__ xfull,
    const int* __restrict__ rowp, const int* __restrict__ csrs,
    const float* __restrict__ eacsr,
    const float* __restrict__ We, const float* __restrict__ att,
    const float* __restrict__ bias, float* __restrict__ spill,
    float* __restrict__ houtf, unsigned short* __restrict__ houtb,
    int nnodes, int E) {
    __shared__ float stash[4][2][GCAP];   // 16 KB
    const int lane = threadIdx.x & 63;
    const int nloc = threadIdx.x >> 6;
    const int node = blockIdx.x * 4 + nloc;
    if (node >= nnodes) return;
    const int rs = rowp[node], re = rowp[node + 1];
    const int deg = re - rs;

    // register-cache We rows 4*lane..4*lane+3 (float2-grouped for pk-fma)
    float2 wreg[4][8];
#pragma unroll
    for (int j = 0; j < 4; ++j) {
        const float4* wp = (const float4*)(We + (size_t)(4 * lane + j) * 16);
#pragma unroll
        for (int q = 0; q < 4; ++q) {
            float4 u = wp[q];
            wreg[j][q * 2 + 0] = make_float2(u.x, u.y);
            wreg[j][q * 2 + 1] = make_float2(u.z, u.w);
        }
    }
    const float4 xr4 = b4f(*(const ushort4*)(xfull + (size_t)node * 512 + 256 + 4 * lane));
    const float4 att4 = *(const float4*)(att + 4 * lane);

    // ---- pass 1: logits ----
    for (int i = rs; i < re; ++i) {
        const int s = csrs[i];
        const float4 xl4 = b4f(*(const ushort4*)(xfull + (size_t)s * 512 + 4 * lane));
        const float4* ep = (const float4*)(eacsr + (size_t)i * 16);  // wave-uniform addr
        float2 ev[8];
#pragma unroll
        for (int q = 0; q < 4; ++q) {
            float4 u = ep[q];
            ev[q * 2 + 0] = make_float2(u.x, u.y);
            ev[q * 2 + 1] = make_float2(u.z, u.w);
        }
        float2 a0 = make_float2(0.f, 0.f), a1 = a0, a2 = a0, a3 = a0;
#pragma unroll
        for (int k = 0; k < 8; ++k) {
            a0.x += ev[k].x * wreg[0][k].x; a0.y += ev[k].y * wreg[0][k].y;
            a1.x += ev[k].x * wreg[1][k].x; a1.y += ev[k].y * wreg[1][k].y;
            a2.x += ev[k].x * wreg[2][k].x; a2.y += ev[k].y * wreg[2][k].y;
            a3.x += ev[k].x * wreg[3][k].x; a3.y += ev[k].y * wreg[3][k].y;
        }
        float sx = xl4.x + xr4.x + a0.x + a0.y;
        float sy = xl4.y + xr4.y + a1.x + a1.y;
        float sz = xl4.z + xr4.z + a2.x + a2.y;
        float sw = xl4.w + xr4.w + a3.x + a3.y;
        sx = fmaxf(sx, 0.2f * sx); sy = fmaxf(sy, 0.2f * sy);
        sz = fmaxf(sz, 0.2f * sz); sw = fmaxf(sw, 0.2f * sw);
        float tv = sx * att4.x + sy * att4.y + sz * att4.z + sw * att4.w;
        tv += __shfl_xor(tv, 1);  tv += __shfl_xor(tv, 2);  tv += __shfl_xor(tv, 4);
        tv += __shfl_xor(tv, 8);  tv += __shfl_xor(tv, 16);
        const int idx = i - rs;
        if (lane == 0)       { if (idx < GCAP) stash[nloc][0][idx] = tv; else spill[i] = tv; }
        else if (lane == 32) { if (idx < GCAP) stash[nloc][1][idx] = tv; else spill[(size_t)E + i] = tv; }
    }

    // ---- pass 2: per-head max & exp-sum ----
    const int h = lane >> 5, l = lane & 31;
    float mx = -INFINITY;
    for (int idx = l; idx < deg; idx += 32) {
        float v = (idx < GCAP) ? stash[nloc][h][idx] : spill[(size_t)h * E + rs + idx];
        mx = fmaxf(mx, v);
    }
    mx = fmaxf(mx, __shfl_xor(mx, 1));  mx = fmaxf(mx, __shfl_xor(mx, 2));
    mx = fmaxf(mx, __shfl_xor(mx, 4));  mx = fmaxf(mx, __shfl_xor(mx, 8));
    mx = fmaxf(mx, __shfl_xor(mx, 16));
    float sum = 0.f;
    for (int idx = l; idx < deg; idx += 32) {
        float v = (idx < GCAP) ? stash[nloc][h][idx] : spill[(size_t)h * E + rs + idx];
        sum += __expf(v - mx);
    }
    sum += __shfl_xor(sum, 1);  sum += __shfl_xor(sum, 2);  sum += __shfl_xor(sum, 4);
    sum += __shfl_xor(sum, 8);  sum += __shfl_xor(sum, 16);
    const float inv = (deg > 0) ? 1.f / sum : 0.f;

    // ---- pass 3: weighted aggregate (rows L2-hot), dual chains ----
    float4 acc0 = make_float4(0.f, 0.f, 0.f, 0.f), acc1 = acc0;
    int i = rs;
    for (; i + 1 < re; i += 2) {
        const int idx = i - rs;
        const float l0 = (idx < GCAP) ? stash[nloc][h][idx] : spill[(size_t)h * E + i];
        const float l1 = (idx + 1 < GCAP) ? stash[nloc][h][idx + 1] : spill[(size_t)h * E + i + 1];
        const float w0 = __expf(l0 - mx) * inv;
        const float w1 = __expf(l1 - mx) * inv;
        const int s0 = csrs[i], s1 = csrs[i + 1];
        const float4 x0 = b4f(*(const ushort4*)(xfull + (size_t)s0 * 512 + 4 * lane));
        const float4 x1 = b4f(*(const ushort4*)(xfull + (size_t)s1 * 512 + 4 * lane));
        acc0.x += w0 * x0.x; acc0.y += w0 * x0.y; acc0.z += w0 * x0.z; acc0.w += w0 * x0.w;
        acc1.x += w1 * x1.x; acc1.y += w1 * x1.y; acc1.z += w1 * x1.z; acc1.w += w1 * x1.w;
    }
    if (i < re) {
        const int idx = i - rs;
        const float l0 = (idx < GCAP) ? stash[nloc][h][idx] : spill[(size_t)h * E + i];
        const float w0 = __expf(l0 - mx) * inv;
        const int s0 = csrs[i];
        const float4 x0 = b4f(*(const ushort4*)(xfull + (size_t)s0 * 512 + 4 * lane));
        acc0.x += w0 * x0.x; acc0.y += w0 * x0.y; acc0.z += w0 * x0.z; acc0.w += w0 * x0.w;
    }
    float ox = acc0.x + acc1.x, oy = acc0.y + acc1.y;
    float oz = acc0.z + acc1.z, ow = acc0.w + acc1.w;
    // mean over heads: lane l (head0) pairs with lane l^32 (head1, same channels)
    ox += __shfl_xor(ox, 32); oy += __shfl_xor(oy, 32);
    oz += __shfl_xor(oz, 32); ow += __shfl_xor(ow, 32);
    if (lane < 32) {
        float4 bu = *(const float4*)(bias + 4 * lane);
        float4 o;
        o.x = fmaxf(0.5f * ox + bu.x, 0.f);
        o.y = fmaxf(0.5f * oy + bu.y, 0.f);
        o.z = fmaxf(0.5f * oz + bu.z, 0.f);
        o.w = fmaxf(0.5f * ow + bu.w, 0.f);
        if (houtf) *(float4*)(houtf + (size_t)node * 128 + 4 * lane) = o;
        if (houtb) *(ushort4*)(houtb + (size_t)node * 128 + 4 * lane) =
            make_ushort4(f2bf(o.x), f2bf(o.y), f2bf(o.z), f2bf(o.w));
    }
}

// ---------------- FiLM: hbf = bf16(gm*h + bm); gm|bm fused in xgb [N,256] ----
__global__ void film_kernel(const float4* __restrict__ h, const float4* __restrict__ xgb,
                            ushort4* __restrict__ hbf, int n4) {
    for (int i = blockIdx.x * blockDim.x + threadIdx.x; i < n4; i += gridDim.x * blockDim.x) {
        const int row = i >> 5, c4 = i & 31;
        float4 hv = h[i];
        float4 g = xgb[row * 64 + c4];
        float4 b = xgb[row * 64 + 32 + c4];
        float ox = g.x * hv.x + b.x, oy = g.y * hv.y + b.y;
        float oz = g.z * hv.z + b.z, ow = g.w * hv.w + b.w;
        hbf[i] = make_ushort4(f2bf(ox), f2bf(oy), f2bf(oz), f2bf(ow));
    }
}

// ---------------- column sum of h[rows,128] -> col[128] ----------------
__global__ __launch_bounds__(256) void colsum_kernel(const float* __restrict__ h,
                                                     float* __restrict__ col, int rows) {
    int c = threadIdx.x & 127;
    int r = blockIdx.x * 2 + (threadIdx.x >> 7);
    float s = 0.f;
    for (; r < rows; r += gridDim.x * 2) s += h[(size_t)r * 128 + c];
    atomicAdd(&col[c], s);
}

// ---------------- out = dot(col/N, q2_W) + q2_b ----------------
__global__ __launch_bounds__(128) void final_kernel(const float* __restrict__ col,
                                                    const float* __restrict__ q2w,
                                                    const float* __restrict__ q2b,
                                                    float* __restrict__ out, float invn) {
    __shared__ float red[128];
    int t = threadIdx.x;
    red[t] = col[t] * invn * q2w[t];
    __syncthreads();
    for (int off = 64; off > 0; off >>= 1) {
        if (t < off) red[t] += red[t + off];
        __syncthreads();
    }
    if (t == 0) out[0] = red[0] + q2b[0];
}

extern "C" void kernel_launch(void* const* d_in, const int* in_sizes, int n_in,
                              void* d_out, int out_size, void* d_ws, size_t ws_size,
                              hipStream_t stream) {
    const int N = in_sizes[0] / 128;   // 20000
    const int E = in_sizes[1] / 2;     // 320000

    typedef const float* fp;
    fp x      = (fp)d_in[0];
    const int* ei = (const int*)d_in[1];
    fp ea     = (fp)d_in[2];
    fp action = (fp)d_in[3];
    fp inp_W  = (fp)d_in[4];
    fp inp_b  = (fp)d_in[5];
    fp ap_W = (fp)d_in[27], ap_b = (fp)d_in[28];
    fp g_W  = (fp)d_in[29], g_b  = (fp)d_in[30];
    fp be_W = (fp)d_in[31], be_b = (fp)d_in[32];
    fp q1_W = (fp)d_in[33], q1_b = (fp)d_in[34];
    fp q2_W = (fp)d_in[35], q2_b = (fp)d_in[36];

    char* base = (char*)d_ws;
    size_t off = 0;
    auto alloc = [&](size_t bytes) { char* p = base + off; off = (off + bytes + 255) & ~(size_t)255; return p; };
    float* h    = (float*)alloc((size_t)N * 128 * 4);             // f32 gat out (film input)
    unsigned short* xfb = (unsigned short*)alloc((size_t)N * 512 * 2);  // fused xl|xr bf16
    float* xgb  = (float*)alloc((size_t)N * 256 * 4);             // fused gamma|beta / q1 out
    float* col  = (float*)alloc(128 * 4);
    int* deg    = (int*)alloc((size_t)N * 4);
    int* rowp   = (int*)alloc((size_t)(N + 1) * 4);
    int* cur    = (int*)alloc((size_t)N * 4);
    int* csrs   = (int*)alloc((size_t)E * 4);
    float* eacsr = (float*)alloc((size_t)E * 16 * 4);             // edge_attr in CSR order
    float* spill = (float*)alloc((size_t)2 * E * 4);              // logit spill (deg>512 only)
    unsigned short* hbf = (unsigned short*)alloc((size_t)N * 128 * 2);
    unsigned short* xbf = (unsigned short*)alloc((size_t)N * 128 * 2);  // x bf16, later a bf16
    unsigned short* wbf = (unsigned short*)alloc(262144 * 2);
    float* abuf = (float*)xfb;             // ap f32 out: xfb region dead at FiLM stage
    unsigned short* abf = xbf;             // x_bf dead after inp gemm
    (void)ws_size; (void)n_in; (void)out_size;

    unsigned short* winp = wbf;            // 128x128
    unsigned short* w1l  = wbf + 16384;    // 256x128 | w1r contiguous -> [512,128]
    unsigned short* w1r  = w1l + 32768;
    unsigned short* w2l  = w1r + 32768;
    unsigned short* w2r  = w2l + 32768;
    unsigned short* wal  = w2r + 32768;
    unsigned short* war  = wal + 32768;
    unsigned short* wg   = war + 32768;    // 128x128 | wbe contiguous -> [256,128]
    unsigned short* wbe  = wg + 16384;
    unsigned short* wq1  = wbe + 16384;

    const int* src = ei;
    const int* dst = ei + E;

    CvtDescs cd;
    int ce = 0;
    auto addc = [&](const float* s, unsigned short* d, int n) { cd.src[ce] = s; cd.dst[ce] = d; cd.n4[ce] = n / 4; ++ce; };
    addc(x, xbf, N * 128);
    addc(inp_W, winp, 16384);
    addc((fp)d_in[6],  w1l, 32768); addc((fp)d_in[8],  w1r, 32768);
    addc((fp)d_in[13], w2l, 32768); addc((fp)d_in[15], w2r, 32768);
    addc((fp)d_in[20], wal, 32768); addc((fp)d_in[22], war, 32768);
    addc(g_W, wg, 16384); addc(be_W, wbe, 16384); addc(q1_W, wq1, 16384);
    cd.cnt = ce;
    cvt_many_kernel<<<2048, 256, 0, stream>>>(cd);

    hipMemsetAsync(deg, 0, (size_t)N * 4, stream);
    hist_kernel<<<(E + 255) / 256, 256, 0, stream>>>(dst, deg, E);
    scan_kernel<<<1, 1024, 0, stream>>>(deg, rowp, cur, N);
    scatter_kernel<<<(E + 255) / 256, 256, 0, stream>>>(src, dst, cur, (const float4*)ea,
                                                        csrs, (float4*)eacsr, E);

    const int my = (N + 127) / 128;
    const int nodeg = (N + 3) / 4;

    auto run_gat = [&](const float* We, const float* at, const float* bi,
                       float* hf, unsigned short* hb) {
        gat_fused_kernel<<<nodeg, 256, 0, stream>>>(xfb, rowp, csrs, eacsr, We, at, bi,
                                                    spill, hf, hb, N, E);
    };

    // h0 = relu(x @ inp_W^T + inp_b) -> bf16
    gemm_mfma_kernel<true, false, true><<<dim3(2, my), 256, 0, stream>>>(
        xbf, winp, inp_b, inp_b, 128, nullptr, hbf, N, 128, 128);

    // s1
    gemm_mfma_kernel<false, false, true><<<dim3(8, my), 256, 0, stream>>>(
        hbf, w1l, (fp)d_in[7], (fp)d_in[9], 256, nullptr, xfb, N, 512, 128);
    run_gat((fp)d_in[10], (fp)d_in[11], (fp)d_in[12], nullptr, hbf);
    // s2 (gat writes h f32 for FiLM)
    gemm_mfma_kernel<false, false, true><<<dim3(8, my), 256, 0, stream>>>(
        hbf, w2l, (fp)d_in[14], (fp)d_in[16], 256, nullptr, xfb, N, 512, 128);
    run_gat((fp)d_in[17], (fp)d_in[18], (fp)d_in[19], h, nullptr);

    // FiLM: a = relu(action@ap^T+ap_b) -> abf; fused gamma|beta gemm -> xgb; film -> hbf
    gemm_kernel<16, true, true><<<dim3(2, (N + 63) / 64), 256, 0, stream>>>(
        action, ap_W, ap_b, abuf, abf, N, 128, 16);
    gemm_mfma_kernel<false, true, false><<<dim3(4, my), 256, 0, stream>>>(
        abf, wg, g_b, be_b, 128, xgb, nullptr, N, 256, 128);
    film_kernel<<<1024, 256, 0, stream>>>((const float4*)h, (const float4*)xgb,
                                          (ushort4*)hbf, N * 128 / 4);

    // sa
    gemm_mfma_kernel<false, false, true><<<dim3(8, my), 256, 0, stream>>>(
        hbf, wal, (fp)d_in[21], (fp)d_in[23], 256, nullptr, xfb, N, 512, 128);
    run_gat((fp)d_in[24], (fp)d_in[25], (fp)d_in[26], nullptr, hbf);

    // q1 + scalar head via column-sum trick
    gemm_mfma_kernel<true, true, false><<<dim3(2, my), 256, 0, stream>>>(
        hbf, wq1, q1_b, q1_b, 128, xgb, nullptr, N, 128, 128);
    hipMemsetAsync(col, 0, 128 * 4, stream);
    colsum_kernel<<<256, 256, 0, stream>>>(xgb, col, N);
    final_kernel<<<1, 128, 0, stream>>>(col, q2_W, q2_b, (float*)d_out, 1.0f / (float)N);
}

// Round 8
// 711.958 us; speedup vs baseline: 1.1582x; 1.1582x over previous
//
#include <hip/hip_runtime.h>
#include <hip/hip_bf16.h>

// EdgeAwareCritic: 3x GATv2 (H=2 heads, HID=128) + FiLM + MLP head, scalar output.
// fp32 inputs; GEMMs in bf16 MFMA. GAT per layer:
//   K1: edge-parallel MFMA logits, xl gathered in fp8 (halves gather bytes)
//   K2: per-node exact softmax + weighted aggregate (bf16 gathers)
// FiLM fused into an in-place MFMA gemm; q1+q2+mean fused into one gemm.

typedef __attribute__((ext_vector_type(8))) short bf16x8;   // 8 bf16 = 4 VGPR
typedef __attribute__((ext_vector_type(4))) float f32x4;
typedef __attribute__((ext_vector_type(2))) float f32x2;

__device__ __forceinline__ unsigned short f2bf(float f) {
    union { float f; unsigned int i; } v; v.f = f;
    unsigned int x = v.i;
    x += 0x7fffu + ((x >> 16) & 1u);   // round-to-nearest-even
    return (unsigned short)(x >> 16);
}
__device__ __forceinline__ float4 b4f(ushort4 u) {
    union { unsigned int i; float f; } a, b, c, d;
    a.i = (unsigned int)u.x << 16; b.i = (unsigned int)u.y << 16;
    c.i = (unsigned int)u.z << 16; d.i = (unsigned int)u.w << 16;
    return make_float4(a.f, b.f, c.f, d.f);
}
__device__ __forceinline__ unsigned char f2fp8(float f) {
    return (unsigned char)(__builtin_amdgcn_cvt_pk_fp8_f32(f, f, 0, false) & 0xFF);
}

// ---------------- multi-tensor fp32 -> bf16 convert (RNE) ----------------
#define MAXCVT 12
struct CvtDescs {
    const float* src[MAXCVT];
    unsigned short* dst[MAXCVT];
    int n4[MAXCVT];
    int cnt;
};
__global__ __launch_bounds__(256) void cvt_many_kernel(CvtDescs d) {
    const int tid = blockIdx.x * blockDim.x + threadIdx.x;
    const int stride = gridDim.x * blockDim.x;
    for (int e = 0; e < d.cnt; ++e) {
        const float4* s = (const float4*)d.src[e];
        ushort4* o = (ushort4*)d.dst[e];
        const int n = d.n4[e];
        for (int i = tid; i < n; i += stride) {
            float4 v = s[i];
            o[i] = make_ushort4(f2bf(v.x), f2bf(v.y), f2bf(v.z), f2bf(v.w));
        }
    }
}

// ---- row-pad convert: [rows,16] f32 -> [rows,32] bf16 (cols 16..31 = 0) ----
struct PadDescs {
    const float* src[4];
    unsigned short* dst[4];
    int rows[4];
    int cnt;
};
__global__ __launch_bounds__(256) void cvt_pad_kernel(PadDescs d) {
    const int tid = blockIdx.x * blockDim.x + threadIdx.x;
    const int stride = gridDim.x * blockDim.x;
    const ushort4 z = make_ushort4(0, 0, 0, 0);
    for (int e = 0; e < d.cnt; ++e) {
        const float4* s = (const float4*)d.src[e];
        ushort4* o = (ushort4*)d.dst[e];
        const int rows = d.rows[e];
        for (int r = tid; r < rows; r += stride) {
            const float4* sp = s + (size_t)r * 4;
            ushort4* op = o + (size_t)r * 8;
#pragma unroll
            for (int q = 0; q < 4; ++q) {
                float4 v = sp[q];
                op[q] = make_ushort4(f2bf(v.x), f2bf(v.y), f2bf(v.z), f2bf(v.w));
            }
#pragma unroll
            for (int q = 4; q < 8; ++q) op[q] = z;
        }
    }
}

// ---------------- CSR build ----------------
__global__ void hist_kernel(const int* __restrict__ dst, int* __restrict__ deg, int n) {
    int i = blockIdx.x * blockDim.x + threadIdx.x;
    if (i < n) atomicAdd(&deg[dst[i]], 1);
}

__global__ __launch_bounds__(1024) void scan_kernel(const int* __restrict__ deg,
                                                    int* __restrict__ rowp,
                                                    int* __restrict__ cur, int n) {
    __shared__ int sums[1024];
    const int t = threadIdx.x;
    const int PER = 20;
    int base = t * PER;
    int local[PER];
    int run = 0;
#pragma unroll
    for (int i = 0; i < PER; ++i) {
        int v = (base + i < n) ? deg[base + i] : 0;
        local[i] = run; run += v;
    }
    sums[t] = run; __syncthreads();
    for (int off = 1; off < 1024; off <<= 1) {
        int v = (t >= off) ? sums[t - off] : 0;
        __syncthreads();
        sums[t] += v;
        __syncthreads();
    }
    int offs = (t > 0) ? sums[t - 1] : 0;
#pragma unroll
    for (int i = 0; i < PER; ++i) {
        int idx = base + i;
        if (idx < n) { int v = offs + local[i]; rowp[idx] = v; cur[idx] = v; }
    }
    if (t == 0) rowp[n] = sums[1023];
}

// scatter: CSR src/dst lists + edge_attr rows -> CSR order, bf16, K-padded to 32
__global__ void scatter_kernel(const int* __restrict__ src, const int* __restrict__ dst,
                               int* __restrict__ cur, const float4* __restrict__ ea,
                               int* __restrict__ csrs, int* __restrict__ csrd,
                               ushort4* __restrict__ eacsr, int n) {
    int i = blockIdx.x * blockDim.x + threadIdx.x;
    if (i < n) {
        int d = dst[i];
        int p = atomicAdd(&cur[d], 1);
        csrs[p] = src[i];
        csrd[p] = d;
        const float4* er = ea + (size_t)i * 4;
        ushort4* eo = eacsr + (size_t)p * 8;
        const ushort4 z = make_ushort4(0, 0, 0, 0);
#pragma unroll
        for (int q = 0; q < 4; ++q) {
            float4 v = er[q];
            eo[q] = make_ushort4(f2bf(v.x), f2bf(v.y), f2bf(v.z), f2bf(v.w));
        }
#pragma unroll
        for (int q = 4; q < 8; ++q) eo[q] = z;
    }
}

// ---------------- bf16 MFMA GEMM: C = A@W^T + bias -> bf16 (+fp8 for n<256) ----
template <bool RELU, bool WF8>
__global__ __launch_bounds__(256) void gemm_mfma_kernel(
    const unsigned short* __restrict__ A, const unsigned short* __restrict__ W,
    const float* __restrict__ bias0, const float* __restrict__ bias1, int bsplit,
    unsigned short* __restrict__ Cbf, unsigned char* __restrict__ Cf8,
    int M, int N, int K) {
    const int t = threadIdx.x;
    const int wave = t >> 6, lane = t & 63;
    const int lo = lane & 15, quad = lane >> 4;
    const int m0 = blockIdx.y * 128 + wave * 32;
    const int n0 = blockIdx.x * 64;

    f32x4 acc[2][4];
#pragma unroll
    for (int i = 0; i < 2; ++i)
#pragma unroll
        for (int j = 0; j < 4; ++j) acc[i][j] = (f32x4){0.f, 0.f, 0.f, 0.f};

    for (int k0 = 0; k0 < K; k0 += 32) {
        bf16x8 af[2], bfr[4];
#pragma unroll
        for (int mi = 0; mi < 2; ++mi) {
            const int mb = m0 + mi * 16;
            if (mb < M)
                af[mi] = *(const bf16x8*)(A + (size_t)(mb + lo) * K + k0 + quad * 8);
            else
                af[mi] = (bf16x8){0, 0, 0, 0, 0, 0, 0, 0};
        }
#pragma unroll
        for (int ni = 0; ni < 4; ++ni)
            bfr[ni] = *(const bf16x8*)(W + (size_t)(n0 + ni * 16 + lo) * K + k0 + quad * 8);
#pragma unroll
        for (int mi = 0; mi < 2; ++mi)
#pragma unroll
            for (int ni = 0; ni < 4; ++ni)
                acc[mi][ni] = __builtin_amdgcn_mfma_f32_16x16x32_bf16(af[mi], bfr[ni], acc[mi][ni], 0, 0, 0);
    }

    float bn[4];
#pragma unroll
    for (int ni = 0; ni < 4; ++ni) {
        const int n = n0 + ni * 16 + lo;
        const float* bp = (n < bsplit) ? bias0 : bias1;
        const int bi = (n < bsplit) ? n : n - bsplit;
        bn[ni] = bp[bi];
    }
#pragma unroll
    for (int mi = 0; mi < 2; ++mi) {
        const int mb = m0 + mi * 16;
        if (mb >= M) continue;
#pragma unroll
        for (int ni = 0; ni < 4; ++ni) {
            const int n = n0 + ni * 16 + lo;
#pragma unroll
            for (int r = 0; r < 4; ++r) {
                float o = acc[mi][ni][r] + bn[ni];
                if (RELU) o = fmaxf(o, 0.f);
                const int row = mb + quad * 4 + r;
                Cbf[(size_t)row * N + n] = f2bf(o);
                if (WF8 && n < 256) Cf8[(size_t)row * 256 + n] = f2fp8(o);
            }
        }
    }
}

// ---------------- FiLM gemm: hbf = bf16((a@Wg^T+gb)*h + (a@Wb^T+bb)), in place ----
__global__ __launch_bounds__(256) void gemm_film_kernel(
    const unsigned short* __restrict__ A, const unsigned short* __restrict__ Wg,
    const unsigned short* __restrict__ Wb, const float* __restrict__ gb,
    const float* __restrict__ bb, unsigned short* __restrict__ hbf, int M) {
    const int K = 128, N = 128;
    const int t = threadIdx.x;
    const int wave = t >> 6, lane = t & 63;
    const int lo = lane & 15, quad = lane >> 4;
    const int m0 = blockIdx.y * 128 + wave * 32;
    const int n0 = blockIdx.x * 64;

    f32x4 accg[2][4], accb[2][4];
#pragma unroll
    for (int i = 0; i < 2; ++i)
#pragma unroll
        for (int j = 0; j < 4; ++j) { accg[i][j] = (f32x4){0.f,0.f,0.f,0.f}; accb[i][j] = accg[i][j]; }

    for (int k0 = 0; k0 < K; k0 += 32) {
        bf16x8 af[2], bg4[4];
#pragma unroll
        for (int mi = 0; mi < 2; ++mi) {
            const int mb = m0 + mi * 16;
            af[mi] = (mb < M) ? *(const bf16x8*)(A + (size_t)(mb + lo) * K + k0 + quad * 8)
                              : (bf16x8){0,0,0,0,0,0,0,0};
        }
#pragma unroll
        for (int ni = 0; ni < 4; ++ni)
            bg4[ni] = *(const bf16x8*)(Wg + (size_t)(n0 + ni * 16 + lo) * K + k0 + quad * 8);
#pragma unroll
        for (int mi = 0; mi < 2; ++mi)
#pragma unroll
            for (int ni = 0; ni < 4; ++ni)
                accg[mi][ni] = __builtin_amdgcn_mfma_f32_16x16x32_bf16(af[mi], bg4[ni], accg[mi][ni], 0, 0, 0);
#pragma unroll
        for (int ni = 0; ni < 4; ++ni)
            bg4[ni] = *(const bf16x8*)(Wb + (size_t)(n0 + ni * 16 + lo) * K + k0 + quad * 8);
#pragma unroll
        for (int mi = 0; mi < 2; ++mi)
#pragma unroll
            for (int ni = 0; ni < 4; ++ni)
                accb[mi][ni] = __builtin_amdgcn_mfma_f32_16x16x32_bf16(af[mi], bg4[ni], accb[mi][ni], 0, 0, 0);
    }

#pragma unroll
    for (int mi = 0; mi < 2; ++mi) {
        const int mb = m0 + mi * 16;
        if (mb >= M) continue;
#pragma unroll
        for (int ni = 0; ni < 4; ++ni) {
            const int n = n0 + ni * 16 + lo;
            const float g = gb[n], b = bb[n];
#pragma unroll
            for (int r = 0; r < 4; ++r) {
                const size_t idx = (size_t)(mb + quad * 4 + r) * N + n;
                union { unsigned int i; float f; } hv; hv.i = (unsigned int)hbf[idx] << 16;
                float o = (accg[mi][ni][r] + g) * hv.f + (accb[mi][ni][r] + b);
                hbf[idx] = f2bf(o);
            }
        }
    }
}

// ---------------- q1 gemm + q2 head: atomicAdd(out, sum(relu(h@q1^T+b1)*q2w)) ----
__global__ __launch_bounds__(256) void gemm_q1_kernel(
    const unsigned short* __restrict__ A, const unsigned short* __restrict__ W,
    const float* __restrict__ q1b, const float* __restrict__ q2w,
    float* __restrict__ outsum, int M) {
    const int K = 128, N = 128;
    const int t = threadIdx.x;
    const int wave = t >> 6, lane = t & 63;
    const int lo = lane & 15, quad = lane >> 4;
    const int m0 = blockIdx.y * 128 + wave * 32;
    const int n0 = blockIdx.x * 64;
    __shared__ float red[4];

    f32x4 acc[2][4];
#pragma unroll
    for (int i = 0; i < 2; ++i)
#pragma unroll
        for (int j = 0; j < 4; ++j) acc[i][j] = (f32x4){0.f, 0.f, 0.f, 0.f};

    for (int k0 = 0; k0 < K; k0 += 32) {
        bf16x8 af[2], bfr[4];
#pragma unroll
        for (int mi = 0; mi < 2; ++mi) {
            const int mb = m0 + mi * 16;
            af[mi] = (mb < M) ? *(const bf16x8*)(A + (size_t)(mb + lo) * K + k0 + quad * 8)
                              : (bf16x8){0,0,0,0,0,0,0,0};
        }
#pragma unroll
        for (int ni = 0; ni < 4; ++ni)
            bfr[ni] = *(const bf16x8*)(W + (size_t)(n0 + ni * 16 + lo) * K + k0 + quad * 8);
#pragma unroll
        for (int mi = 0; mi < 2; ++mi)
#pragma unroll
            for (int ni = 0; ni < 4; ++ni)
                acc[mi][ni] = __builtin_amdgcn_mfma_f32_16x16x32_bf16(af[mi], bfr[ni], acc[mi][ni], 0, 0, 0);
    }

    float partial = 0.f;
#pragma unroll
    for (int mi = 0; mi < 2; ++mi) {
        const int mb = m0 + mi * 16;
        if (mb >= M) continue;
#pragma unroll
        for (int ni = 0; ni < 4; ++ni) {
            const int n = n0 + ni * 16 + lo;
            const float b = q1b[n], w = q2w[n];
#pragma unroll
            for (int r = 0; r < 4; ++r)
                partial += fmaxf(acc[mi][ni][r] + b, 0.f) * w;
        }
    }
    partial += __shfl_xor(partial, 1);  partial += __shfl_xor(partial, 2);
    partial += __shfl_xor(partial, 4);  partial += __shfl_xor(partial, 8);
    partial += __shfl_xor(partial, 16); partial += __shfl_xor(partial, 32);
    if (lane == 0) red[wave] = partial;
    __syncthreads();
    if (t == 0) atomicAdd(outsum, red[0] + red[1] + red[2] + red[3]);
}

// ---------------- fp32 vector GEMM (only for ap: K=16) ----------------
template <int BK, bool RELU, bool WBF16>
__global__ __launch_bounds__(256) void gemm_kernel(const float* __restrict__ A,
                                                   const float* __restrict__ W,
                                                   const float* __restrict__ bp,
                                                   float* __restrict__ C,
                                                   unsigned short* __restrict__ Cbf,
                                                   int M, int N, int K) {
    __shared__ float As[BK][68];
    __shared__ float Ws[BK][68];
    const int t = threadIdx.x;
    const int m0 = blockIdx.y * 64;
    const int n0 = blockIdx.x * 64;
    const int tx = t & 15, ty = t >> 4;
    float acc[4][4];
#pragma unroll
    for (int i = 0; i < 4; ++i)
#pragma unroll
        for (int j = 0; j < 4; ++j) acc[i][j] = 0.f;

    for (int k0 = 0; k0 < K; k0 += BK) {
        const int r = t >> 2, cc = (t & 3) * 4;
        const int arow = m0 + r;
        float4 av = (arow < M) ? *(const float4*)(A + (size_t)arow * K + k0 + cc)
                               : make_float4(0.f, 0.f, 0.f, 0.f);
        As[cc + 0][r] = av.x; As[cc + 1][r] = av.y;
        As[cc + 2][r] = av.z; As[cc + 3][r] = av.w;
        float4 wv = *(const float4*)(W + (size_t)(n0 + r) * K + k0 + cc);
        Ws[cc + 0][r] = wv.x; Ws[cc + 1][r] = wv.y;
        Ws[cc + 2][r] = wv.z; Ws[cc + 3][r] = wv.w;
        __syncthreads();
#pragma unroll
        for (int k = 0; k < BK; ++k) {
            float4 a4 = *(const float4*)&As[k][ty * 4];
            float4 b4 = *(const float4*)&Ws[k][tx * 4];
            float a_[4] = {a4.x, a4.y, a4.z, a4.w};
            float b_[4] = {b4.x, b4.y, b4.z, b4.w};
#pragma unroll
            for (int i = 0; i < 4; ++i)
#pragma unroll
                for (int j = 0; j < 4; ++j) acc[i][j] += a_[i] * b_[j];
        }
        __syncthreads();
    }
    float4 bj = *(const float4*)(bp + n0 + tx * 4);
    float bb[4] = {bj.x, bj.y, bj.z, bj.w};
#pragma unroll
    for (int i = 0; i < 4; ++i) {
        int row = m0 + ty * 4 + i;
        if (row < M) {
            float o[4];
#pragma unroll
            for (int j = 0; j < 4; ++j) {
                o[j] = acc[i][j] + bb[j];
                if (RELU) o[j] = fmaxf(o[j], 0.f);
            }
            *(float4*)(C + (size_t)row * N + n0 + tx * 4) = make_float4(o[0], o[1], o[2], o[3]);
            if (WBF16)
                *(ushort4*)(Cbf + (size_t)row * N + n0 + tx * 4) =
                    make_ushort4(f2bf(o[0]), f2bf(o[1]), f2bf(o[2]), f2bf(o[3]));
        }
    }
}

// ---------------- GAT K1: MFMA edge logits, fp8 xl gathers ----------------
// Wave handles 16 CSR positions/batch. em block t via one 16x16x32 bf16 MFMA
// (A = WePad, B = eaCSR row). C-layout: lane (lo,quad) holds channels
// t*16+quad*4..+3 of edge p0+lo. xl gathered fp8 (halved bytes), xr bf16 (L1-hot).
__global__ __launch_bounds__(256, 4) void gat_logit_kernel(
    const unsigned short* __restrict__ xfull, const unsigned char* __restrict__ xl8,
    const int* __restrict__ csrs, const int* __restrict__ csrd,
    const unsigned short* __restrict__ eacsr, const unsigned short* __restrict__ wepad,
    const float* __restrict__ att, float* __restrict__ logit, int E) {
    __shared__ float attl[256];
    const int tid = threadIdx.x;
    attl[tid] = att[tid];
    const int wave = tid >> 6, lane = tid & 63;
    const int lo = lane & 15, quad = lane >> 4;

    bf16x8 wef[16];
#pragma unroll
    for (int t = 0; t < 16; ++t)
        wef[t] = *(const bf16x8*)(wepad + (size_t)(t * 16 + lo) * 32 + quad * 8);
    __syncthreads();

    const int nb = (E + 15) / 16;
    for (int b = blockIdx.x * 4 + wave; b < nb; b += gridDim.x * 4) {
        const int p0 = b * 16;
        const int p = min(p0 + lo, E - 1);
        const int s = csrs[p], d = csrd[p];
        const bf16x8 eaf = *(const bf16x8*)(eacsr + (size_t)p * 32 + quad * 8);
        float ph0 = 0.f, ph1 = 0.f;
#pragma unroll
        for (int t = 0; t < 16; ++t) {
            f32x4 D = __builtin_amdgcn_mfma_f32_16x16x32_bf16(
                wef[t], eaf, (f32x4){0.f, 0.f, 0.f, 0.f}, 0, 0, 0);
            const int c0 = t * 16 + quad * 4;
            const unsigned int u8 = *(const unsigned int*)(xl8 + (size_t)s * 256 + c0);
            const f32x2 l01 = __builtin_amdgcn_cvt_pk_f32_fp8(u8, false);
            const f32x2 l23 = __builtin_amdgcn_cvt_pk_f32_fp8(u8, true);
            const float4 xr4 = b4f(*(const ushort4*)(xfull + (size_t)d * 512 + 256 + c0));
            const float4 at4 = *(const float4*)&attl[c0];
            float vx = l01.x + xr4.x + D[0];
            float vy = l01.y + xr4.y + D[1];
            float vz = l23.x + xr4.z + D[2];
            float vw = l23.y + xr4.w + D[3];
            vx = fmaxf(vx, 0.2f * vx); vy = fmaxf(vy, 0.2f * vy);
            vz = fmaxf(vz, 0.2f * vz); vw = fmaxf(vw, 0.2f * vw);
            const float pt = vx * at4.x + vy * at4.y + vz * at4.z + vw * at4.w;
            if (t < 8) ph0 += pt; else ph1 += pt;
        }
        ph0 += __shfl_xor(ph0, 16); ph0 += __shfl_xor(ph0, 32);
        ph1 += __shfl_xor(ph1, 16); ph1 += __shfl_xor(ph1, 32);
        if (p0 + lo < E) {
            if (quad == 0) logit[p0 + lo] = ph0;
            else if (quad == 1) logit[(size_t)E + p0 + lo] = ph1;
        }
    }
}

// ---------------- GAT K2: per-node softmax + weighted gather-sum (bf16) ----
__global__ __launch_bounds__(256) void gat_na_kernel(
    const unsigned short* __restrict__ xfull,
    const int* __restrict__ rowp, const int* __restrict__ csrs,
    const float* __restrict__ wgt, const float* __restrict__ bias,
    unsigned short* __restrict__ houtb, int nnodes, int E) {
    const int lane = threadIdx.x & 63;
    const int node = blockIdx.x * 4 + (threadIdx.x >> 6);
    if (node >= nnodes) return;
    const int rs = rowp[node], re = rowp[node + 1];
    const int h = lane >> 5, l = lane & 31;
    const float* lg = wgt + (size_t)h * E;

    float mx = -INFINITY;
    for (int i = rs + l; i < re; i += 32) mx = fmaxf(mx, lg[i]);
    mx = fmaxf(mx, __shfl_xor(mx, 1));  mx = fmaxf(mx, __shfl_xor(mx, 2));
    mx = fmaxf(mx, __shfl_xor(mx, 4));  mx = fmaxf(mx, __shfl_xor(mx, 8));
    mx = fmaxf(mx, __shfl_xor(mx, 16));
    float sum = 0.f;
    for (int i = rs + l; i < re; i += 32) sum += __expf(lg[i] - mx);
    sum += __shfl_xor(sum, 1);  sum += __shfl_xor(sum, 2);  sum += __shfl_xor(sum, 4);
    sum += __shfl_xor(sum, 8);  sum += __shfl_xor(sum, 16);
    const float inv = (re > rs) ? 1.f / sum : 0.f;

    float4 acc0 = make_float4(0.f, 0.f, 0.f, 0.f), acc1 = acc0;
    int i = rs;
    for (; i + 1 < re; i += 2) {
        const int s0 = csrs[i], s1 = csrs[i + 1];
        const float w0 = __expf(lg[i] - mx) * inv;
        const float w1 = __expf(lg[i + 1] - mx) * inv;
        const float4 x0 = b4f(*(const ushort4*)(xfull + (size_t)s0 * 512 + 4 * lane));
        const float4 x1 = b4f(*(const ushort4*)(xfull + (size_t)s1 * 512 + 4 * lane));
        acc0.x += w0 * x0.x; acc0.y += w0 * x0.y; acc0.z += w0 * x0.z; acc0.w += w0 * x0.w;
        acc1.x += w1 * x1.x; acc1.y += w1 * x1.y; acc1.z += w1 * x1.z; acc1.w += w1 * x1.w;
    }
    if (i < re) {
        const int s0 = csrs[i];
        const float w0 = __expf(lg[i] - mx) * inv;
        const float4 x0 = b4f(*(const ushort4*)(xfull + (size_t)s0 * 512 + 4 * lane));
        acc0.x += w0 * x0.x; acc0.y += w0 * x0.y; acc0.z += w0 * x0.z; acc0.w += w0 * x0.w;
    }
    float ox = acc0.x + acc1.x, oy = acc0.y + acc1.y;
    float oz = acc0.z + acc1.z, ow = acc0.w + acc1.w;
    ox += __shfl_xor(ox, 32); oy += __shfl_xor(oy, 32);
    oz += __shfl_xor(oz, 32); ow += __shfl_xor(ow, 32);
    if (lane < 32) {
        float4 bu = *(const float4*)(bias + 4 * lane);
        *(ushort4*)(houtb + (size_t)node * 128 + 4 * lane) = make_ushort4(
            f2bf(fmaxf(0.5f * ox + bu.x, 0.f)), f2bf(fmaxf(0.5f * oy + bu.y, 0.f)),
            f2bf(fmaxf(0.5f * oz + bu.z, 0.f)), f2bf(fmaxf(0.5f * ow + bu.w, 0.f)));
    }
}

// ---------------- out = sum/N + q2_b ----------------
__global__ void final_kernel(const float* __restrict__ s, const float* __restrict__ q2b,
                             float* __restrict__ out, float invn) {
    out[0] = s[0] * invn + q2b[0];
}

extern "C" void kernel_launch(void* const* d_in, const int* in_sizes, int n_in,
                              void* d_out, int out_size, void* d_ws, size_t ws_size,
                              hipStream_t stream) {
    const int N = in_sizes[0] / 128;   // 20000
    const int E = in_sizes[1] / 2;     // 320000

    typedef const float* fp;
    fp x      = (fp)d_in[0];
    const int* ei = (const int*)d_in[1];
    fp ea     = (fp)d_in[2];
    fp action = (fp)d_in[3];
    fp inp_W  = (fp)d_in[4];
    fp inp_b  = (fp)d_in[5];
    fp ap_W = (fp)d_in[27], ap_b = (fp)d_in[28];
    fp g_W  = (fp)d_in[29], g_b  = (fp)d_in[30];
    fp be_W = (fp)d_in[31], be_b = (fp)d_in[32];
    fp q1_W = (fp)d_in[33], q1_b = (fp)d_in[34];
    fp q2_W = (fp)d_in[35], q2_b = (fp)d_in[36];

    char* base = (char*)d_ws;
    size_t off = 0;
    auto alloc = [&](size_t bytes) { char* p = base + off; off = (off + bytes + 255) & ~(size_t)255; return p; };
    unsigned short* xfb = (unsigned short*)alloc((size_t)N * 512 * 2);  // fused xl|xr bf16
    unsigned char*  xl8 = (unsigned char*)alloc((size_t)N * 256);       // xl fp8 copy
    float* col  = (float*)alloc(128 * 4);
    int* deg    = (int*)alloc((size_t)N * 4);
    int* rowp   = (int*)alloc((size_t)(N + 1) * 4);
    int* cur    = (int*)alloc((size_t)N * 4);
    int* csrs   = (int*)alloc((size_t)E * 4);
    int* csrd   = (int*)alloc((size_t)E * 4);
    unsigned short* eacsr = (unsigned short*)alloc((size_t)E * 32 * 2); // ea bf16 K-pad, CSR order
    float* wgt  = (float*)alloc((size_t)2 * E * 4);                     // logits
    unsigned short* hbf = (unsigned short*)alloc((size_t)N * 128 * 2);
    unsigned short* xbf = (unsigned short*)alloc((size_t)N * 128 * 2);  // x bf16, later a bf16
    unsigned short* wbf = (unsigned short*)alloc((262144 + 3 * 8192) * 2);
    float* abuf = (float*)xfb;             // ap f32 out: xfb dead at FiLM stage
    unsigned short* abf = xbf;             // x_bf dead after inp gemm
    (void)ws_size; (void)n_in; (void)out_size;

    unsigned short* winp = wbf;            // 128x128
    unsigned short* w1l  = wbf + 16384;    // [512,128] fused pairs
    unsigned short* w1r  = w1l + 32768;
    unsigned short* w2l  = w1r + 32768;
    unsigned short* w2r  = w2l + 32768;
    unsigned short* wal  = w2r + 32768;
    unsigned short* war  = wal + 32768;
    unsigned short* wg   = war + 32768;    // 128x128
    unsigned short* wbe  = wg + 16384;
    unsigned short* wq1  = wbe + 16384;
    unsigned short* wep1 = wq1 + 16384;    // 3x [256,32] K-padded We
    unsigned short* wep2 = wep1 + 8192;
    unsigned short* wep3 = wep2 + 8192;

    const int* src = ei;
    const int* dst = ei + E;

    CvtDescs cd;
    int ce = 0;
    auto addc = [&](const float* s, unsigned short* d, int n) { cd.src[ce] = s; cd.dst[ce] = d; cd.n4[ce] = n / 4; ++ce; };
    addc(x, xbf, N * 128);
    addc(inp_W, winp, 16384);
    addc((fp)d_in[6],  w1l, 32768); addc((fp)d_in[8],  w1r, 32768);
    addc((fp)d_in[13], w2l, 32768); addc((fp)d_in[15], w2r, 32768);
    addc((fp)d_in[20], wal, 32768); addc((fp)d_in[22], war, 32768);
    addc(g_W, wg, 16384); addc(be_W, wbe, 16384); addc(q1_W, wq1, 16384);
    cd.cnt = ce;
    cvt_many_kernel<<<2048, 256, 0, stream>>>(cd);

    PadDescs pd;
    pd.src[0] = (fp)d_in[10]; pd.dst[0] = wep1; pd.rows[0] = 256;
    pd.src[1] = (fp)d_in[17]; pd.dst[1] = wep2; pd.rows[1] = 256;
    pd.src[2] = (fp)d_in[24]; pd.dst[2] = wep3; pd.rows[2] = 256;
    pd.cnt = 3;
    cvt_pad_kernel<<<64, 256, 0, stream>>>(pd);

    hipMemsetAsync(deg, 0, (size_t)N * 4, stream);
    hist_kernel<<<(E + 255) / 256, 256, 0, stream>>>(dst, deg, E);
    scan_kernel<<<1, 1024, 0, stream>>>(deg, rowp, cur, N);
    scatter_kernel<<<(E + 255) / 256, 256, 0, stream>>>(src, dst, cur, (const float4*)ea,
                                                        csrs, csrd, (ushort4*)eacsr, E);

    const int my = (N + 127) / 128;
    const int nodeg = (N + 3) / 4;

    auto run_gat = [&](const unsigned short* wep, const float* at, const float* bi,
                       unsigned short* hb) {
        gat_logit_kernel<<<2500, 256, 0, stream>>>(xfb, xl8, csrs, csrd, eacsr, wep, at, wgt, E);
        gat_na_kernel<<<nodeg, 256, 0, stream>>>(xfb, rowp, csrs, wgt, bi, hb, N, E);
    };

    // h0 = relu(x @ inp_W^T + inp_b) -> bf16
    gemm_mfma_kernel<true, false><<<dim3(2, my), 256, 0, stream>>>(
        xbf, winp, inp_b, inp_b, 128, hbf, nullptr, N, 128, 128);

    // s1
    gemm_mfma_kernel<false, true><<<dim3(8, my), 256, 0, stream>>>(
        hbf, w1l, (fp)d_in[7], (fp)d_in[9], 256, xfb, xl8, N, 512, 128);
    run_gat(wep1, (fp)d_in[11], (fp)d_in[12], hbf);
    // s2
    gemm_mfma_kernel<false, true><<<dim3(8, my), 256, 0, stream>>>(
        hbf, w2l, (fp)d_in[14], (fp)d_in[16], 256, xfb, xl8, N, 512, 128);
    run_gat(wep2, (fp)d_in[18], (fp)d_in[19], hbf);

    // FiLM: a = relu(action@ap^T+ap_b) -> abf; fused gamma/beta gemm in-place on hbf
    gemm_kernel<16, true, true><<<dim3(2, (N + 63) / 64), 256, 0, stream>>>(
        action, ap_W, ap_b, abuf, abf, N, 128, 16);
    gemm_film_kernel<<<dim3(2, my), 256, 0, stream>>>(abf, wg, wbe, g_b, be_b, hbf, N);

    // sa
    gemm_mfma_kernel<false, true><<<dim3(8, my), 256, 0, stream>>>(
        hbf, wal, (fp)d_in[21], (fp)d_in[23], 256, xfb, xl8, N, 512, 128);
    run_gat(wep3, (fp)d_in[25], (fp)d_in[26], hbf);

    // q1 + q2 + mean fused
    hipMemsetAsync(col, 0, 4, stream);
    gemm_q1_kernel<<<dim3(2, my), 256, 0, stream>>>(hbf, wq1, q1_b, q2_W, col, N);
    final_kernel<<<1, 1, 0, stream>>>(col, q2_b, (float*)d_out, 1.0f / (float)N);
}